// Round 1
// baseline (740.557 us; speedup 1.0000x reference)
//
#include <hip/hip_runtime.h>
#include <hip/hip_bf16.h>

#define FEAT 1024
#define EMBED 128

typedef __attribute__((ext_vector_type(8))) short short8;
typedef __attribute__((ext_vector_type(4))) float floatx4;

__device__ inline short f2bf(float f) {
    __hip_bfloat16 h = __float2bfloat16(f);
    return *reinterpret_cast<short*>(&h);
}

// --- kernel 1: weight fp32 -> bf16 -------------------------------------------
__global__ void convert_weight_kernel(const float* __restrict__ w,
                                      ushort* __restrict__ wb, int n) {
    int i = blockIdx.x * blockDim.x + threadIdx.x;
    if (i < n) {
        __hip_bfloat16 h = __float2bfloat16(w[i]);
        wb[i] = *reinterpret_cast<ushort*>(&h);
    }
}

// --- kernel 2: h = x @ W^T via bf16 MFMA -------------------------------------
// block = 256 threads = 4 waves; wave w computes rows [blk*64 + w*16, +16) x all
// 128 embed cols as 8 accumulators of 16x16.
// A-frag: A[m][k], m = lane&15, k = (lane>>4)*8 + j   (j = 0..7)
// B-frag: B[k][n], n = lane&15, k = (lane>>4)*8 + j   (B[k][n] = W[n][k])
// C/D   : D[row][col], col = lane&15, row = (lane>>4)*4 + r
__launch_bounds__(256)
__global__ void gemm_xwT_kernel(const float* __restrict__ x,
                                const ushort* __restrict__ wb,
                                float* __restrict__ h, int n_nodes) {
    const int lane = threadIdx.x & 63;
    const int wave = threadIdx.x >> 6;
    const int q    = lane >> 4;
    const int m    = lane & 15;
    const int base = blockIdx.x * 64 + wave * 16;

    int row = base + m;
    int row_ld = row < n_nodes ? row : (n_nodes - 1);  // clamp for safe loads
    const float* xp = x + (size_t)row_ld * FEAT + q * 8;

    floatx4 acc[8];
#pragma unroll
    for (int t = 0; t < 8; ++t) acc[t] = (floatx4)(0.0f);

    for (int kc = 0; kc < FEAT; kc += 32) {
        // A fragment: 8 consecutive fp32 -> bf16
        float4 a0 = *(const float4*)(xp + kc);
        float4 a1 = *(const float4*)(xp + kc + 4);
        short8 afrag;
        afrag[0] = f2bf(a0.x); afrag[1] = f2bf(a0.y);
        afrag[2] = f2bf(a0.z); afrag[3] = f2bf(a0.w);
        afrag[4] = f2bf(a1.x); afrag[5] = f2bf(a1.y);
        afrag[6] = f2bf(a1.z); afrag[7] = f2bf(a1.w);

#pragma unroll
        for (int t = 0; t < 8; ++t) {
            // W row (embed) = t*16 + m, cols kc + q*8 .. +7 : 16B contiguous
            short8 bfrag = *(const short8*)(wb + (size_t)(t * 16 + m) * FEAT + kc + q * 8);
            acc[t] = __builtin_amdgcn_mfma_f32_16x16x32_bf16(afrag, bfrag, acc[t], 0, 0, 0);
        }
    }

#pragma unroll
    for (int t = 0; t < 8; ++t) {
#pragma unroll
        for (int r = 0; r < 4; ++r) {
            int rr = base + q * 4 + r;
            if (rr < n_nodes)
                h[(size_t)rr * EMBED + t * 16 + m] = acc[t][r];
        }
    }
}

// --- kernel 3: scatter-add messages ------------------------------------------
// 2 edges per 256-thread block; 128 threads per edge (one per embed dim).
__launch_bounds__(256)
__global__ void scatter_edges_kernel(const int* __restrict__ adj_row,
                                     const int* __restrict__ adj_col,
                                     const float* __restrict__ adj_vals,
                                     const float* __restrict__ h,
                                     float* __restrict__ out, int n_edges) {
    int e = blockIdx.x * 2 + (threadIdx.x >> 7);
    if (e >= n_edges) return;
    int f = threadIdx.x & 127;
    int r = adj_row[e];
    int c = adj_col[e];
    float v = adj_vals[e];
    float msg = v * h[(size_t)c * EMBED + f];
    atomicAdd(&out[(size_t)r * EMBED + f], msg);
}

extern "C" void kernel_launch(void* const* d_in, const int* in_sizes, int n_in,
                              void* d_out, int out_size, void* d_ws, size_t ws_size,
                              hipStream_t stream) {
    const float* x        = (const float*)d_in[0];
    const float* w        = (const float*)d_in[1];
    const int*   adj_row  = (const int*)d_in[2];
    const int*   adj_col  = (const int*)d_in[3];
    const float* adj_vals = (const float*)d_in[4];

    const int n_nodes = in_sizes[0] / FEAT;
    const int n_edges = in_sizes[2];
    float* out = (float*)d_out;

    // workspace layout: [bf16 weight 256KB][h 25.6MB]
    ushort* wb = (ushort*)d_ws;
    float*  h  = (float*)((char*)d_ws + (size_t)EMBED * FEAT * sizeof(ushort));

    // zero output (harness poisons it with 0xAA before every launch)
    hipMemsetAsync(d_out, 0, (size_t)out_size * sizeof(float), stream);

    convert_weight_kernel<<<(EMBED * FEAT + 255) / 256, 256, 0, stream>>>(
        w, wb, EMBED * FEAT);

    gemm_xwT_kernel<<<(n_nodes + 63) / 64, 256, 0, stream>>>(x, wb, h, n_nodes);

    scatter_edges_kernel<<<(n_edges + 1) / 2, 256, 0, stream>>>(
        adj_row, adj_col, adj_vals, h, out, n_edges);
}

// Round 2
// 522.520 us; speedup vs baseline: 1.4173x; 1.4173x over previous
//
#include <hip/hip_runtime.h>
#include <hip/hip_bf16.h>

#define FEAT 1024
#define EMBED 128
#define CAP 64          // per-node bucket capacity (Poisson mean deg = 16)
#define OVF_CAP 4096    // overflow list capacity

typedef __attribute__((ext_vector_type(8))) short short8;
typedef __attribute__((ext_vector_type(4))) float floatx4;

__device__ inline ushort f2bf(float f) {
    __hip_bfloat16 h = __float2bfloat16(f);
    return *reinterpret_cast<ushort*>(&h);
}

// --- kernel 1: W fp32 -> bf16, swizzled into MFMA-fragment-linear order ------
// wbs[((s*8 + t)*64 + lane)*8 + j] = bf16(W[t*16 + (lane&15)][s*32 + (lane>>4)*8 + j])
// so the GEMM B-frag load is a single coalesced 16B/lane load.
__global__ void swizzle_weight_kernel(const float* __restrict__ w,
                                      ushort* __restrict__ wbs) {
    int gid = blockIdx.x * blockDim.x + threadIdx.x;   // 32*8*64 = 16384 threads
    int l = gid & 63;
    int t = (gid >> 6) & 7;
    int s = gid >> 9;
    int row = t * 16 + (l & 15);
    int col = s * 32 + (l >> 4) * 8;
    const float* src = w + (size_t)row * FEAT + col;
    float4 v0 = *(const float4*)(src);
    float4 v1 = *(const float4*)(src + 4);
    short8 o;
    o[0] = f2bf(v0.x); o[1] = f2bf(v0.y); o[2] = f2bf(v0.z); o[3] = f2bf(v0.w);
    o[4] = f2bf(v1.x); o[5] = f2bf(v1.y); o[6] = f2bf(v1.z); o[7] = f2bf(v1.w);
    *(short8*)(wbs + (size_t)gid * 8) = o;
}

// --- kernel 2: h = x @ W^T via bf16 MFMA -------------------------------------
// block = 256 = 4 waves; wave handles 16 rows x 128 embeds (8 accumulators).
// A-frag: A[m][k], m=lane&15, k=(lane>>4)*8+j ; per-lane direct global loads
// (16 rows x 128B contiguous per k-step -> fully dense segments).
// B-frag: single 16B/lane load from swizzled wbs (L2-resident, 256KB).
// C/D: col=lane&15, row=(lane>>4)*4+r  (verified by R1 pass).
__launch_bounds__(256, 4)
__global__ void gemm_xwT_kernel(const float* __restrict__ x,
                                const ushort* __restrict__ wbs,
                                float* __restrict__ h, int n_nodes) {
    const int lane = threadIdx.x & 63;
    const int wave = threadIdx.x >> 6;
    const int q    = lane >> 4;
    const int m    = lane & 15;
    const int base = blockIdx.x * 64 + wave * 16;

    int row = base + m;
    int row_ld = row < n_nodes ? row : (n_nodes - 1);
    const float*  xp = x + (size_t)row_ld * FEAT + q * 8;
    const ushort* bp = wbs + lane * 8;

    floatx4 acc[8];
#pragma unroll
    for (int t = 0; t < 8; ++t) acc[t] = (floatx4)(0.0f);

    float4 a0 = *(const float4*)(xp);
    float4 a1 = *(const float4*)(xp + 4);

    for (int s = 0; s < 32; ++s) {
        float4 na0, na1;
        if (s < 31) {                       // prefetch next A chunk
            na0 = *(const float4*)(xp + (s + 1) * 32);
            na1 = *(const float4*)(xp + (s + 1) * 32 + 4);
        }
        short8 af;
        af[0] = f2bf(a0.x); af[1] = f2bf(a0.y);
        af[2] = f2bf(a0.z); af[3] = f2bf(a0.w);
        af[4] = f2bf(a1.x); af[5] = f2bf(a1.y);
        af[6] = f2bf(a1.z); af[7] = f2bf(a1.w);

        const ushort* bs = bp + s * 4096;   // 8 tiles * 512 ushorts
#pragma unroll
        for (int t = 0; t < 8; ++t) {
            short8 bf = *(const short8*)(bs + t * 512);
            acc[t] = __builtin_amdgcn_mfma_f32_16x16x32_bf16(af, bf, acc[t], 0, 0, 0);
        }
        a0 = na0; a1 = na1;
    }

#pragma unroll
    for (int t = 0; t < 8; ++t) {
#pragma unroll
        for (int r = 0; r < 4; ++r) {
            int rr = base + q * 4 + r;
            if (rr < n_nodes)
                h[(size_t)rr * EMBED + t * 16 + m] = acc[t][r];
        }
    }
}

// --- kernel 3: bucket edges by destination -----------------------------------
__global__ void bucket_fill_kernel(const int* __restrict__ adj_row,
                                   const int* __restrict__ adj_col,
                                   const float* __restrict__ adj_vals,
                                   int* __restrict__ cnt,
                                   int2* __restrict__ bucket,
                                   int* __restrict__ ovf_cnt,
                                   int* __restrict__ ovf_list,
                                   int n_edges) {
    int e = blockIdx.x * blockDim.x + threadIdx.x;
    if (e >= n_edges) return;
    int r = adj_row[e];
    int slot = atomicAdd(&cnt[r], 1);
    if (slot < CAP) {
        bucket[(size_t)r * CAP + slot] = make_int2(adj_col[e], __float_as_int(adj_vals[e]));
    } else {
        int oi = atomicAdd(ovf_cnt, 1);
        if (oi < OVF_CAP) ovf_list[oi] = e;
    }
}

// --- kernel 4: per-node gather-accumulate (no atomics) -----------------------
// 2 nodes per 256-thread block; thread f accumulates over the node's bucket.
__launch_bounds__(256)
__global__ void gather_kernel(const int* __restrict__ cnt,
                              const int2* __restrict__ bucket,
                              const float* __restrict__ h,
                              float* __restrict__ out, int n_nodes) {
    int node = blockIdx.x * 2 + (threadIdx.x >> 7);
    if (node >= n_nodes) return;
    int f = threadIdx.x & 127;
    int c = cnt[node];
    if (c > CAP) c = CAP;
    const int2* bp = bucket + (size_t)node * CAP;
    float acc = 0.0f;
    for (int j = 0; j < c; ++j) {
        int2 ev = bp[j];                                  // broadcast 8B
        acc = fmaf(__int_as_float(ev.y), h[(size_t)ev.x * EMBED + f], acc);
    }
    out[(size_t)node * EMBED + f] = acc;                  // dense write, no memset needed
}

// --- kernel 5: exact fixup for (astronomically unlikely) bucket overflow -----
__global__ void overflow_fixup_kernel(const int* __restrict__ ovf_cnt,
                                      const int* __restrict__ ovf_list,
                                      const int* __restrict__ adj_row,
                                      const int* __restrict__ adj_col,
                                      const float* __restrict__ adj_vals,
                                      const float* __restrict__ h,
                                      float* __restrict__ out) {
    int n = *ovf_cnt;
    if (n > OVF_CAP) n = OVF_CAP;
    int f = threadIdx.x;                                  // 128 threads
    for (int i = blockIdx.x; i < n; i += gridDim.x) {
        int e = ovf_list[i];
        atomicAdd(&out[(size_t)adj_row[e] * EMBED + f],
                  adj_vals[e] * h[(size_t)adj_col[e] * EMBED + f]);
    }
}

extern "C" void kernel_launch(void* const* d_in, const int* in_sizes, int n_in,
                              void* d_out, int out_size, void* d_ws, size_t ws_size,
                              hipStream_t stream) {
    const float* x        = (const float*)d_in[0];
    const float* w        = (const float*)d_in[1];
    const int*   adj_row  = (const int*)d_in[2];
    const int*   adj_col  = (const int*)d_in[3];
    const float* adj_vals = (const float*)d_in[4];

    const int n_nodes = in_sizes[0] / FEAT;
    const int n_edges = in_sizes[2];
    float* out = (float*)d_out;

    // workspace layout (bytes):
    //   [wbs 256KB][h n*128*4][cnt n*4][ovf_cnt 4][ovf_list 16KB][pad 4][bucket n*CAP*8]
    char* ws = (char*)d_ws;
    ushort* wbs = (ushort*)ws;
    size_t off = 262144;
    float* h = (float*)(ws + off);
    off += (size_t)n_nodes * EMBED * sizeof(float);
    char* meta = ws + off;
    int* cnt      = (int*)meta;
    int* ovf_cnt  = (int*)(meta + (size_t)n_nodes * 4);
    int* ovf_list = ovf_cnt + 1;
    size_t meta_bytes = (size_t)n_nodes * 4 + 4 + OVF_CAP * 4 + 4;  // +4 pad -> 8B align
    int2* bucket = (int2*)(meta + meta_bytes);

    // zero cnt + ovf_cnt (+list, cheap) in one async memset
    hipMemsetAsync(meta, 0, meta_bytes, stream);

    swizzle_weight_kernel<<<64, 256, 0, stream>>>(w, wbs);

    gemm_xwT_kernel<<<(n_nodes + 63) / 64, 256, 0, stream>>>(x, wbs, h, n_nodes);

    bucket_fill_kernel<<<(n_edges + 255) / 256, 256, 0, stream>>>(
        adj_row, adj_col, adj_vals, cnt, bucket, ovf_cnt, ovf_list, n_edges);

    gather_kernel<<<(n_nodes + 1) / 2, 256, 0, stream>>>(cnt, bucket, h, out, n_nodes);

    overflow_fixup_kernel<<<64, 128, 0, stream>>>(
        ovf_cnt, ovf_list, adj_row, adj_col, adj_vals, h, out);
}

// Round 3
// 415.403 us; speedup vs baseline: 1.7827x; 1.2579x over previous
//
#include <hip/hip_runtime.h>
#include <hip/hip_bf16.h>

#define FEAT 1024
#define EMBED 128
#define CAP 64          // per-node bucket capacity (Poisson mean deg = 16)
#define OVF_CAP 4096    // overflow list capacity

typedef __attribute__((ext_vector_type(8))) short short8;
typedef __attribute__((ext_vector_type(4))) float floatx4;

__device__ inline ushort f2bf(float f) {
    __hip_bfloat16 h = __float2bfloat16(f);
    return *reinterpret_cast<ushort*>(&h);
}
__device__ inline float bfbits_lo(uint u) {        // low 16 bits as bf16 -> f32
    uint v = u << 16; return *reinterpret_cast<float*>(&v);
}
__device__ inline float bfbits_hi(uint u) {        // high 16 bits as bf16 -> f32
    uint v = u & 0xffff0000u; return *reinterpret_cast<float*>(&v);
}

// --- kernel 1: W fp32 -> bf16, swizzled into MFMA-fragment-linear order ------
// wbs[((s*8 + t)*64 + lane)*8 + j] = bf16(W[t*16 + (lane&15)][s*32 + (lane>>4)*8 + j])
__global__ void swizzle_weight_kernel(const float* __restrict__ w,
                                      ushort* __restrict__ wbs) {
    int gid = blockIdx.x * blockDim.x + threadIdx.x;   // 16384 threads
    int l = gid & 63;
    int t = (gid >> 6) & 7;
    int s = gid >> 9;
    int row = t * 16 + (l & 15);
    int col = s * 32 + (l >> 4) * 8;
    const float* src = w + (size_t)row * FEAT + col;
    float4 v0 = *(const float4*)(src);
    float4 v1 = *(const float4*)(src + 4);
    short8 o;
    o[0] = f2bf(v0.x); o[1] = f2bf(v0.y); o[2] = f2bf(v0.z); o[3] = f2bf(v0.w);
    o[4] = f2bf(v1.x); o[5] = f2bf(v1.y); o[6] = f2bf(v1.z); o[7] = f2bf(v1.w);
    *(short8*)(wbs + (size_t)gid * 8) = o;
}

// --- kernel 2: h = x @ W^T via bf16 MFMA, h stored bf16 ----------------------
// block = 256 = 4 waves; wave handles 16 rows x 128 embeds (8 accumulators).
// B-frags for a k-step are loaded as an 8-deep independent batch (MLP=8).
__launch_bounds__(256, 4)
__global__ void gemm_xwT_kernel(const float* __restrict__ x,
                                const ushort* __restrict__ wbs,
                                ushort* __restrict__ hb, int n_nodes) {
    const int lane = threadIdx.x & 63;
    const int wave = threadIdx.x >> 6;
    const int q    = lane >> 4;
    const int m    = lane & 15;
    const int base = blockIdx.x * 64 + wave * 16;

    int row = base + m;
    int row_ld = row < n_nodes ? row : (n_nodes - 1);
    const float*  xp = x + (size_t)row_ld * FEAT + q * 8;
    const ushort* bp = wbs + lane * 8;

    floatx4 acc[8];
#pragma unroll
    for (int t = 0; t < 8; ++t) acc[t] = (floatx4)(0.0f);

    float4 a0 = *(const float4*)(xp);
    float4 a1 = *(const float4*)(xp + 4);

    for (int s = 0; s < 32; ++s) {
        float4 na0, na1;
        if (s < 31) {                       // prefetch next A chunk
            na0 = *(const float4*)(xp + (s + 1) * 32);
            na1 = *(const float4*)(xp + (s + 1) * 32 + 4);
        }
        // batch-load all 8 B fragments (independent -> 8 loads in flight)
        const ushort* bs = bp + s * 4096;
        short8 bf[8];
#pragma unroll
        for (int t = 0; t < 8; ++t) bf[t] = *(const short8*)(bs + t * 512);

        short8 af;
        af[0] = f2bf(a0.x); af[1] = f2bf(a0.y);
        af[2] = f2bf(a0.z); af[3] = f2bf(a0.w);
        af[4] = f2bf(a1.x); af[5] = f2bf(a1.y);
        af[6] = f2bf(a1.z); af[7] = f2bf(a1.w);

#pragma unroll
        for (int t = 0; t < 8; ++t)
            acc[t] = __builtin_amdgcn_mfma_f32_16x16x32_bf16(af, bf[t], acc[t], 0, 0, 0);
        a0 = na0; a1 = na1;
    }

#pragma unroll
    for (int t = 0; t < 8; ++t) {
#pragma unroll
        for (int r = 0; r < 4; ++r) {
            int rr = base + q * 4 + r;
            if (rr < n_nodes)
                hb[(size_t)rr * EMBED + t * 16 + m] = f2bf(acc[t][r]);
        }
    }
}

// --- kernel 3: bucket edges by destination -----------------------------------
__global__ void bucket_fill_kernel(const int* __restrict__ adj_row,
                                   const int* __restrict__ adj_col,
                                   const float* __restrict__ adj_vals,
                                   int* __restrict__ cnt,
                                   int2* __restrict__ bucket,
                                   int* __restrict__ ovf_cnt,
                                   int* __restrict__ ovf_list,
                                   int n_edges) {
    int e = blockIdx.x * blockDim.x + threadIdx.x;
    if (e >= n_edges) return;
    int r = adj_row[e];
    int slot = atomicAdd(&cnt[r], 1);
    if (slot < CAP) {
        bucket[(size_t)r * CAP + slot] = make_int2(adj_col[e], __float_as_int(adj_vals[e]));
    } else {
        int oi = atomicAdd(ovf_cnt, 1);
        if (oi < OVF_CAP) ovf_list[oi] = e;
    }
}

// --- kernel 4: per-node gather-accumulate, MLP-4, bf16 h ---------------------
// 4 nodes per 256-thread block (1 wave per node); lane owns embed dims
// {2*lane, 2*lane+1} via one u32 (bf16x2) load -> 256 B coalesced per row.
__launch_bounds__(256)
__global__ void gather_kernel(const int* __restrict__ cnt,
                              const int2* __restrict__ bucket,
                              const ushort* __restrict__ hb,
                              float* __restrict__ out, int n_nodes) {
    int node = blockIdx.x * 4 + (threadIdx.x >> 6);
    if (node >= n_nodes) return;
    int lane = threadIdx.x & 63;
    int c = cnt[node];
    if (c > CAP) c = CAP;
    const int2* bp = bucket + (size_t)node * CAP;

    float accx = 0.0f, accy = 0.0f;
    int j = 0;
    for (; j + 4 <= c; j += 4) {
        int4 e01 = *(const int4*)(bp + j);       // edges j, j+1
        int4 e23 = *(const int4*)(bp + j + 2);   // edges j+2, j+3
        // 4 independent h-row loads (bf16x2 per lane)
        uint u0 = *(const uint*)(hb + (size_t)e01.x * EMBED + lane * 2);
        uint u1 = *(const uint*)(hb + (size_t)e01.z * EMBED + lane * 2);
        uint u2 = *(const uint*)(hb + (size_t)e23.x * EMBED + lane * 2);
        uint u3 = *(const uint*)(hb + (size_t)e23.z * EMBED + lane * 2);
        float w0 = __int_as_float(e01.y), w1 = __int_as_float(e01.w);
        float w2 = __int_as_float(e23.y), w3 = __int_as_float(e23.w);
        accx = fmaf(w0, bfbits_lo(u0), accx);  accy = fmaf(w0, bfbits_hi(u0), accy);
        accx = fmaf(w1, bfbits_lo(u1), accx);  accy = fmaf(w1, bfbits_hi(u1), accy);
        accx = fmaf(w2, bfbits_lo(u2), accx);  accy = fmaf(w2, bfbits_hi(u2), accy);
        accx = fmaf(w3, bfbits_lo(u3), accx);  accy = fmaf(w3, bfbits_hi(u3), accy);
    }
    for (; j < c; ++j) {
        int2 ev = bp[j];
        uint u = *(const uint*)(hb + (size_t)ev.x * EMBED + lane * 2);
        float w = __int_as_float(ev.y);
        accx = fmaf(w, bfbits_lo(u), accx);
        accy = fmaf(w, bfbits_hi(u), accy);
    }
    *(float2*)(out + (size_t)node * EMBED + lane * 2) = make_float2(accx, accy);
}

// --- kernel 5: exact fixup for bucket overflow (expected n=0) ----------------
__global__ void overflow_fixup_kernel(const int* __restrict__ ovf_cnt,
                                      const int* __restrict__ ovf_list,
                                      const int* __restrict__ adj_row,
                                      const int* __restrict__ adj_col,
                                      const float* __restrict__ adj_vals,
                                      const ushort* __restrict__ hb,
                                      float* __restrict__ out) {
    int n = *ovf_cnt;
    if (n > OVF_CAP) n = OVF_CAP;
    int f = threadIdx.x;                                  // 128 threads
    for (int i = blockIdx.x; i < n; i += gridDim.x) {
        int e = ovf_list[i];
        uint us = hb[(size_t)adj_col[e] * EMBED + f];
        uint v = us << 16;
        atomicAdd(&out[(size_t)adj_row[e] * EMBED + f],
                  adj_vals[e] * *reinterpret_cast<float*>(&v));
    }
}

extern "C" void kernel_launch(void* const* d_in, const int* in_sizes, int n_in,
                              void* d_out, int out_size, void* d_ws, size_t ws_size,
                              hipStream_t stream) {
    const float* x        = (const float*)d_in[0];
    const float* w        = (const float*)d_in[1];
    const int*   adj_row  = (const int*)d_in[2];
    const int*   adj_col  = (const int*)d_in[3];
    const float* adj_vals = (const float*)d_in[4];

    const int n_nodes = in_sizes[0] / FEAT;
    const int n_edges = in_sizes[2];
    float* out = (float*)d_out;

    // workspace layout (bytes):
    //   [wbs 256KB][hb n*128*2][cnt n*4][ovf_cnt 4][ovf_list][pad->16][bucket n*CAP*8]
    char* ws = (char*)d_ws;
    ushort* wbs = (ushort*)ws;
    size_t off = 262144;
    ushort* hb = (ushort*)(ws + off);
    off += (size_t)n_nodes * EMBED * sizeof(ushort);
    char* meta = ws + off;
    int* cnt      = (int*)meta;
    int* ovf_cnt  = (int*)(meta + (size_t)n_nodes * 4);
    int* ovf_list = ovf_cnt + 1;
    size_t meta_bytes = ((size_t)n_nodes * 4 + 4 + OVF_CAP * 4 + 15) & ~(size_t)15;
    int2* bucket = (int2*)(meta + meta_bytes);

    hipMemsetAsync(meta, 0, meta_bytes, stream);

    swizzle_weight_kernel<<<64, 256, 0, stream>>>(w, wbs);

    gemm_xwT_kernel<<<(n_nodes + 63) / 64, 256, 0, stream>>>(x, wbs, hb, n_nodes);

    bucket_fill_kernel<<<(n_edges + 255) / 256, 256, 0, stream>>>(
        adj_row, adj_col, adj_vals, cnt, bucket, ovf_cnt, ovf_list, n_edges);

    gather_kernel<<<(n_nodes + 3) / 4, 256, 0, stream>>>(cnt, bucket, hb, out, n_nodes);

    overflow_fixup_kernel<<<64, 128, 0, stream>>>(
        ovf_cnt, ovf_list, adj_row, adj_col, adj_vals, hb, out);
}